// Round 3
// baseline (6839.043 us; speedup 1.0000x reference)
//
#include <hip/hip_runtime.h>
#include <math.h>

#define NN   16384      // total nodes
#define NE   262144     // edges (no self loops)
#define NB   64         // graphs
#define SEQT 256        // nodes per graph (= seq len)
#define DEP  64
#define DOUT 256        // = HID
#define G3   768        // 3*HID
#define GK   256        // GEMM K (always 256 here)
#define ECAP 32         // GCN edges staged per chunk

typedef _Float16 h2_t   __attribute__((ext_vector_type(2)));
typedef _Float16 f16x4  __attribute__((ext_vector_type(4)));
typedef _Float16 f16x8  __attribute__((ext_vector_type(8)));
typedef float    f32x4  __attribute__((ext_vector_type(4)));

static __device__ __forceinline__ h2_t pk(float a, float b) {
    return (h2_t)__builtin_amdgcn_cvt_pkrtz(a, b);
}

static __device__ __forceinline__ float fast_sigmoid(float v) {
    return __builtin_amdgcn_rcpf(1.f + __expf(-v));
}
static __device__ __forceinline__ float fast_tanh(float v) {
    return 1.f - 2.f * __builtin_amdgcn_rcpf(1.f + __expf(2.f * v));
}

// ---------------------------------------------------------------------------
// degree / CSR build (deg zero-initialized by memset; holds RAW in-degree)
// ---------------------------------------------------------------------------
__global__ void k_count(const int* __restrict__ ei, int* deg) {
    int e = blockIdx.x * 256 + threadIdx.x;
    if (e < NE) atomicAdd(&deg[ei[NE + e]], 1);   // col = dst
}

__global__ __launch_bounds__(1024) void k_scan_offs(const int* __restrict__ deg,
                                                    int* __restrict__ offs,
                                                    float* __restrict__ dinv) {
    __shared__ int lds[1024];
    const int tid = threadIdx.x;
    const int v0 = tid * 16;
    int loc[16];
    int s = 0;
#pragma unroll
    for (int i = 0; i < 16; ++i) {
        int d = deg[v0 + i];                      // raw in-edges
        loc[i] = s;
        s += d;
        dinv[v0 + i] = rsqrtf((float)(d + 1));    // +1 self loop
    }
    lds[tid] = s;
    __syncthreads();
    for (int off = 1; off < 1024; off <<= 1) {
        int x = (tid >= off) ? lds[tid - off] : 0;
        __syncthreads();
        lds[tid] += x;
        __syncthreads();
    }
    int base = lds[tid] - s;                      // exclusive prefix of this thread
#pragma unroll
    for (int i = 0; i < 16; ++i) offs[v0 + i] = base + loc[i];
}

__global__ void k_fill(const int* __restrict__ ei, const int* __restrict__ offs,
                       int* cursor, int* __restrict__ eidx) {
    int e = blockIdx.x * 256 + threadIdx.x;
    if (e < NE) {
        int c = ei[NE + e];
        int pos = offs[c] + atomicAdd(&cursor[c], 1);
        eidx[pos] = e;
    }
}

__global__ void k_bself(const float* __restrict__ WB, float* Bself) {
    int f = threadIdx.x;                          // 256 threads
    float s = 0.f;
#pragma unroll
    for (int d = 0; d < DEP; ++d) s += WB[f * DEP + d];
    Bself[f] = s;
}

// bias fold: bias768[l][j] = b_ih[j] + (j<512 ? b_hh[j] : 0)   (b_hn stays
// separate: the reference scales it by r before adding)
__global__ void k_bias_fold(const float* __restrict__ bi0, const float* __restrict__ bh0,
                            const float* __restrict__ bi1, const float* __restrict__ bh1,
                            const float* __restrict__ bi2, const float* __restrict__ bh2,
                            float* __restrict__ o) {
    int j = blockIdx.x * 256 + threadIdx.x;       // 9 blocks x 256 = 2304
    int l = j / G3, r = j % G3;
    const float* bi = (l == 0) ? bi0 : (l == 1) ? bi1 : bi2;
    const float* bh = (l == 0) ? bh0 : (l == 1) ? bh1 : bh2;
    o[j] = bi[r] + (r < 512 ? bh[r] : 0.f);
}

// ---------------------------------------------------------------------------
// one fused fp32->f16 conversion over all 5 regions
// ---------------------------------------------------------------------------
__global__ void k_cvt_all(const float* __restrict__ x,  const float* __restrict__ wa,
                          const float* __restrict__ w0, const float* __restrict__ w1,
                          const float* __restrict__ w2,
                          _Float16* __restrict__ xo,  _Float16* __restrict__ wao,
                          _Float16* __restrict__ w0o, _Float16* __restrict__ w1o,
                          _Float16* __restrict__ w2o) {
    size_t i = ((size_t)blockIdx.x * 256 + threadIdx.x) * 4;
    const size_t B0 = 4194304, B1 = B0 + 65536, B2 = B1 + 196608, B3 = B2 + 196608;
    const float* in; _Float16* out; size_t off;
    if      (i < B0) { in = x;  out = xo;  off = i; }
    else if (i < B1) { in = wa; out = wao; off = i - B0; }
    else if (i < B2) { in = w0; out = w0o; off = i - B1; }
    else if (i < B3) { in = w1; out = w1o; off = i - B2; }
    else             { in = w2; out = w2o; off = i - B3; }
    float4 v = *(const float4*)(in + off);
    *(h2_t*)(out + off)     = pk(v.x, v.y);
    *(h2_t*)(out + off + 2) = pk(v.z, v.w);
}

// ---------------------------------------------------------------------------
// MFMA f16 GEMM: C[M,N] = A16[M,256] @ B16[N,256]^T (+ bias).
// F16OUT: store f16 (used for xp); else fp32 (used for Ax).
// ---------------------------------------------------------------------------
template <bool F16OUT>
__global__ __launch_bounds__(256) void k_gemm16(const _Float16* __restrict__ A16,
                                                const _Float16* __restrict__ B16,
                                                const float* __restrict__ bias,
                                                void* __restrict__ Cout,
                                                int M, int N) {
    const int tid  = threadIdx.x;
    const int lane = tid & 63;
    const int wv   = tid >> 6;
    const int m0   = blockIdx.x * 128 + wv * 32;
    const int n0   = blockIdx.y * 128;
    const int ml   = lane & 15;
    const int quad = lane >> 4;

    const _Float16* ap0 = A16 + (size_t)(m0 + ml) * GK + quad * 8;
    const _Float16* ap1 = ap0 + (size_t)16 * GK;
    const _Float16* bp0 = B16 + (size_t)(n0 + ml) * GK + quad * 8;

    f32x4 acc[2][8];
#pragma unroll
    for (int i = 0; i < 2; ++i)
#pragma unroll
        for (int j = 0; j < 8; ++j) acc[i][j] = (f32x4){0.f, 0.f, 0.f, 0.f};

#pragma unroll 2
    for (int k0 = 0; k0 < GK; k0 += 32) {
        f16x8 a0 = *(const f16x8*)(ap0 + k0);
        f16x8 a1 = *(const f16x8*)(ap1 + k0);
#pragma unroll
        for (int nf = 0; nf < 8; ++nf) {
            f16x8 bf = *(const f16x8*)(bp0 + (size_t)nf * 16 * GK + k0);
            acc[0][nf] = __builtin_amdgcn_mfma_f32_16x16x32_f16(a0, bf, acc[0][nf], 0, 0, 0);
            acc[1][nf] = __builtin_amdgcn_mfma_f32_16x16x32_f16(a1, bf, acc[1][nf], 0, 0, 0);
        }
    }

#pragma unroll
    for (int mf = 0; mf < 2; ++mf)
#pragma unroll
        for (int nf = 0; nf < 8; ++nf) {
            const int col = n0 + nf * 16 + ml;
            const float bv = bias ? bias[col] : 0.f;
#pragma unroll
            for (int r = 0; r < 4; ++r) {
                const int row = m0 + mf * 16 + quad * 4 + r;
                float v = acc[mf][nf][r] + bv;
                if (F16OUT)
                    ((_Float16*)Cout)[(size_t)row * N + col] = (_Float16)v;
                else
                    ((float*)Cout)[(size_t)row * N + col] = v;
            }
        }
}

// ---------------------------------------------------------------------------
// GCN gather v2: chunked LDS staging, fast_tanh.
// ---------------------------------------------------------------------------
__global__ __launch_bounds__(256) void k_gcn(const float* __restrict__ Ax,
                                             const float* __restrict__ WB,
                                             const float* __restrict__ edge_attr,
                                             const int* __restrict__ ei,
                                             const int* __restrict__ eidx,
                                             const int* __restrict__ offs,
                                             const int* __restrict__ deg,
                                             const float* __restrict__ dinv,
                                             const float* __restrict__ Bself,
                                             const float* __restrict__ gcn_bias,
                                             _Float16* __restrict__ node16) {
    const int v = blockIdx.x;
    const int f = threadIdx.x;

    float wb[64];
#pragma unroll
    for (int d4 = 0; d4 < 16; ++d4) {
        float4 t = *(const float4*)&WB[f * DEP + d4 * 4];
        wb[d4 * 4 + 0] = t.x; wb[d4 * 4 + 1] = t.y;
        wb[d4 * 4 + 2] = t.z; wb[d4 * 4 + 3] = t.w;
    }

    __shared__ float ea_s[ECAP * 64];
    __shared__ int   es_s[ECAP];
    __shared__ int   src_s[ECAP];
    __shared__ float nrm_s[ECAP];

    const int   base = offs[v];
    const int   cnt  = deg[v];                   // raw in-edges
    const float dv   = dinv[v];
    float acc = 0.f;

    for (int c0 = 0; c0 < cnt; c0 += ECAP) {
        const int n = min(ECAP, cnt - c0);
        if (f < n) {
            int e = eidx[base + c0 + f];
            es_s[f] = e;
            int s = ei[e];
            src_s[f] = s;
            nrm_s[f] = dinv[s] * dv;
        }
        __syncthreads();
        for (int idx = f; idx < n * 64; idx += 256) {
            int el = idx >> 6, d = idx & 63;
            ea_s[idx] = edge_attr[(size_t)es_s[el] * DEP + d];
        }
        __syncthreads();
        for (int i = 0; i < n; ++i) {
            float ax = Ax[(size_t)src_s[i] * DOUT + f];   // issued early
            float be = 0.f;
#pragma unroll
            for (int d = 0; d < 64; ++d) be = fmaf(wb[d], ea_s[i * 64 + d], be);
            acc = fmaf(nrm_s[i], fast_tanh(ax * be), acc);
        }
        __syncthreads();                          // before chunk overwrite
    }
    // self loop: norm = dinv^2, Be = rowsum(WB)
    acc += dv * dv * fast_tanh(Ax[(size_t)v * DOUT + f] * Bself[f]);
    float nv = fast_tanh(acc / (float)(cnt + 1) + gcn_bias[f]);
    node16[(size_t)v * DOUT + f] = (_Float16)nv;
}

// ---------------------------------------------------------------------------
// GRU scan v11: PAIRWISE ROW-SPLIT. Two blocks per graph (bid b and b+64,
// same XCD under round-robin). Half h owns w_hh rows {j,256+j,512+j :
// j in [128h,128h+128)}. Per wave: 3 A-frags (r,z,n rows for its 16 j's)
// x 8 kt = 24 MFMA/step -> per-SIMD issue 768 cyc (half of v10's 1536).
//
// In-register gates: C-frag layout (col=lane&15 identical copies,
// row=quad*4+reg) puts r/z/n for j = j0w+quad*4+(m&3) in the SAME lane at
// reg (m&3) of C[0..2] -> 9 cndmask extraction, no LDS for gh.
//
// h exchange per step: own half via LDS h16; partner half via agent-scope
// atomics (MALL) + release/acquire flag. Double-buffered by parity t&1.
// Flag value base+t+2 posted at end of step t certifies BOTH "h(t+1)
// written" AND "h(t) consumed" -> the 2-parity buffer is race-free with
// lockstep-within-+-1 progress. Partner loads issued first; their MALL
// latency hides under own-half MFMAs (own kts = half*4..+4 map exactly to
// the own j-range since k index == h index). Bounded spins prevent hangs.
// 128 blocks <= 256 CUs -> co-resident, no deadlock.
// ---------------------------------------------------------------------------
__global__ __launch_bounds__(512, 2) void k_gru_scan(const _Float16* __restrict__ xp16,
                                                     const float* __restrict__ w_hh,
                                                     const float* __restrict__ b_hh,
                                                     _Float16* __restrict__ y16,
                                                     float* __restrict__ hT_all,
                                                     int layer,
                                                     const float* __restrict__ lin_W,
                                                     const float* __restrict__ lin_b,
                                                     float* __restrict__ out,
                                                     unsigned int* __restrict__ h_ex,
                                                     int* __restrict__ flags,
                                                     float* __restrict__ acc2,
                                                     int* __restrict__ done2) {
    const int tid  = threadIdx.x;
    const int bid  = blockIdx.x;
    const int half = bid >> 6;                   // 0 / 1 (row-half)
    const int b    = bid & 63;                   // graph
    const int lane = tid & 63;
    const int wv   = tid >> 6;                   // wave 0..7
    const int m    = lane & 15;
    const int quad = lane >> 4;
    const int r    = m & 3;                      // C reg select
    const int j0w  = half * 128 + wv * 16;       // wave's j base
    const int j    = j0w + quad * 4 + r;         // this lane's hidden unit

    // --- weights -> A-frags: 3 frags (r,z,n) x 8 kt; row = f*256 + j0w + m
    f16x8 A[3][8];
#pragma unroll
    for (int f = 0; f < 3; ++f) {
        const int row = f * 256 + j0w + m;
#pragma unroll
        for (int kt = 0; kt < 8; ++kt) {
            const float* wp = w_hh + (size_t)row * 256 + kt * 32 + quad * 8;
            float4 a0 = *(const float4*)wp;
            float4 a1 = *(const float4*)(wp + 4);
            union { f16x8 v; h2_t h[4]; } u;
            u.h[0] = pk(a0.x, a0.y); u.h[1] = pk(a0.z, a0.w);
            u.h[2] = pk(a1.x, a1.y); u.h[3] = pk(a1.z, a1.w);
            A[f][kt] = u.v;
        }
    }

    const float bhn = b_hh[512 + j];             // n-gate hidden bias

    __shared__ _Float16 h16[2][128];             // OWN half of h, 2 parities
    __shared__ float    red[1024];               // layer-2 epilogue reduce

    unsigned int* hex_b  = h_ex + (size_t)b * 256;        // [2][128] dwords
    int*          myflag = flags + half * 64 + b;
    int*          pflag  = flags + (half ^ 1) * 64 + b;
    const int     base   = layer * (SEQT + 1);
    const int     ko     = half * 4;             // own kt range
    const int     kp     = (half ^ 1) * 4;       // partner kt range

    // prologue: zero own h(0) (LDS + global parity0), publish "h(0) ready"
    if (tid < 128) h16[0][tid] = (_Float16)0.f;
    if (tid < 64)
        __hip_atomic_store(&hex_b[half * 64 + tid], 0u,
                           __ATOMIC_RELAXED, __HIP_MEMORY_SCOPE_AGENT);
    __syncthreads();
    if (tid == 0)
        __hip_atomic_store(myflag, base + 1,
                           __ATOMIC_RELEASE, __HIP_MEMORY_SCOPE_AGENT);

    const _Float16* xpb  = xp16 + (size_t)b * SEQT * G3;
    _Float16*       yb16 = y16  + (size_t)b * SEQT * DOUT;

    float h_old = 0.f;
    float mx = -1e30f, sm = 0.f;                 // layer-2 pooling accum

    for (int t = 0; t < SEQT; ++t) {
        // xp for this step (consumed after the MFMA phase; ~1k cyc slack)
        const _Float16* xpt = xpb + (size_t)t * G3;
        const float xr = (float)xpt[j];
        const float xz = (float)xpt[256 + j];
        const float xn = (float)xpt[512 + j];

        // wait for partner's h(t)
        if (tid == 0) {
            const int want = base + t + 1;
            int fl = __hip_atomic_load(pflag, __ATOMIC_ACQUIRE,
                                       __HIP_MEMORY_SCOPE_AGENT);
            int g = 0;
            while (fl < want && ++g < (1 << 22)) {
                __builtin_amdgcn_s_sleep(2);
                fl = __hip_atomic_load(pflag, __ATOMIC_ACQUIRE,
                                       __HIP_MEMORY_SCOPE_AGENT);
            }
        }
        __syncthreads();

        // partner-half B loads FIRST (MALL latency hides under own MFMAs)
        const unsigned long long* hq8 =
            (const unsigned long long*)(hex_b + (size_t)(t & 1) * 128);
        union { f16x8 v; unsigned long long q[2]; } Bp[4];
#pragma unroll
        for (int i = 0; i < 4; ++i) {
            const unsigned long long* p = hq8 + (size_t)(kp + i) * 8 + quad * 2;
            Bp[i].q[0] = __hip_atomic_load(p,     __ATOMIC_RELAXED,
                                           __HIP_MEMORY_SCOPE_AGENT);
            Bp[i].q[1] = __hip_atomic_load(p + 1, __ATOMIC_RELAXED,
                                           __HIP_MEMORY_SCOPE_AGENT);
        }

        f32x4 C[3];
#pragma unroll
        for (int f = 0; f < 3; ++f) C[f] = (f32x4){0.f, 0.f, 0.f, 0.f};

        // own half via LDS (k index == h index: own kts cover own j-range)
        const _Float16* hcur = h16[t & 1];
#pragma unroll
        for (int i = 0; i < 4; ++i) {
            union { f16x8 v; float4 f4; } Bo;
            Bo.f4 = *(const float4*)&hcur[i * 32 + quad * 8];
#pragma unroll
            for (int f = 0; f < 3; ++f)
                C[f] = __builtin_amdgcn_mfma_f32_16x16x32_f16(A[f][ko + i], Bo.v, C[f], 0, 0, 0);
        }
        // partner half
#pragma unroll
        for (int i = 0; i < 4; ++i)
#pragma unroll
            for (int f = 0; f < 3; ++f)
                C[f] = __builtin_amdgcn_mfma_f32_16x16x32_f16(A[f][kp + i], Bp[i].v, C[f], 0, 0, 0);

        // in-register extraction: reg (m&3) of C[f] holds gh for this lane's j
        float a01, a23;
        a01 = (r & 1) ? C[0][1] : C[0][0];  a23 = (r & 1) ? C[0][3] : C[0][2];
        const float ghr = (r & 2) ? a23 : a01;
        a01 = (r & 1) ? C[1][1] : C[1][0];  a23 = (r & 1) ? C[1][3] : C[1][2];
        const float ghz = (r & 2) ? a23 : a01;
        a01 = (r & 1) ? C[2][1] : C[2][0];  a23 = (r & 1) ? C[2][3] : C[2][2];
        const float ghn = (r & 2) ? a23 : a01;

        const float rr = fast_sigmoid(xr + ghr);
        const float zz = fast_sigmoid(xz + ghz);
        const float nn = fast_tanh(xn + rr * (ghn + bhn));
        const float hn = nn + zz * (h_old - nn);
        h_old = hn;

        const float hnb = __shfl_xor(hn, 1);     // neighbor j^1's h

        if (m < 4) {                             // unique writer per j
            h16[(t & 1) ^ 1][j - half * 128] = (_Float16)hn;
            if ((m & 1) == 0) {                  // m in {0,2}: packed pair
                union { h2_t h; unsigned int u; } pu;
                pu.h[0] = (_Float16)hn;          // RNE, matches LDS path
                pu.h[1] = (_Float16)hnb;
                __hip_atomic_store(&hex_b[(((t + 1) & 1)) * 128 + (j >> 1)], pu.u,
                                   __ATOMIC_RELAXED, __HIP_MEMORY_SCOPE_AGENT);
            }
            if (layer < 2) {
                yb16[(size_t)t * DOUT + j] = (_Float16)hn;
                if (t == SEQT - 1) hT_all[layer * NB * 256 + b * 256 + j] = hn;
            }
        }
        if (layer == 2) { mx = fmaxf(mx, hn); sm += hn; }

        __syncthreads();                         // drains all waves' stores
        if (tid == 0)
            __hip_atomic_store(myflag, base + t + 2,
                               __ATOMIC_RELEASE, __HIP_MEMORY_SCOPE_AGENT);
    }

    if (layer == 2) {
        // partial pooling+linear over this block's 128 j's, then pair-combine
        float c0 = 0.f, c1 = 0.f;
        if (m < 4) {
            const float hT0v = hT_all[b * 256 + j];
            const float hT1v = hT_all[NB * 256 + b * 256 + j];
            const float av   = sm * (1.f / 256.f);
            c0 = lin_W[j] * hT0v + lin_W[256 + j] * hT1v + lin_W[512 + j] * h_old
               + lin_W[768 + j] * mx + lin_W[1024 + j] * av;
            c1 = lin_W[1280 + j] * hT0v + lin_W[1536 + j] * hT1v + lin_W[1792 + j] * h_old
               + lin_W[2048 + j] * mx + lin_W[2304 + j] * av;
        }
        red[tid] = c0; red[512 + tid] = c1;
        __syncthreads();
        for (int s = 256; s > 0; s >>= 1) {
            if (tid < s) { red[tid] += red[tid + s]; red[512 + tid] += red[512 + tid + s]; }
            __syncthreads();
        }
        if (tid == 0) {
            atomicAdd(&acc2[b * 2],     red[0]);
            atomicAdd(&acc2[b * 2 + 1], red[512]);
            __hip_atomic_fetch_add(&done2[b], 1,
                                   __ATOMIC_RELEASE, __HIP_MEMORY_SCOPE_AGENT);
            if (half == 0) {
                int g = 0;
                while (__hip_atomic_load(&done2[b], __ATOMIC_ACQUIRE,
                                         __HIP_MEMORY_SCOPE_AGENT) < 2 &&
                       ++g < (1 << 22)) { __builtin_amdgcn_s_sleep(2); }
                const float l0 = lin_b[0] + __hip_atomic_load(&acc2[b * 2],
                                     __ATOMIC_RELAXED, __HIP_MEMORY_SCOPE_AGENT);
                const float l1 = lin_b[1] + __hip_atomic_load(&acc2[b * 2 + 1],
                                     __ATOMIC_RELAXED, __HIP_MEMORY_SCOPE_AGENT);
                const float m2 = fmaxf(l0, l1);
                const float e0 = __expf(l0 - m2), e1 = __expf(l1 - m2);
                const float s = e0 + e1;
                out[b * 2 + 0] = e0 / s;
                out[b * 2 + 1] = e1 / s;
            }
        }
    }
}

// ---------------------------------------------------------------------------
extern "C" void kernel_launch(void* const* d_in, const int* in_sizes, int n_in,
                              void* d_out, int out_size, void* d_ws, size_t ws_size,
                              hipStream_t stream) {
    const float* x         = (const float*)d_in[0];
    const float* edge_attr = (const float*)d_in[1];
    const int*   ei        = (const int*)d_in[2];
    const float* WA        = (const float*)d_in[3];
    const float* WB        = (const float*)d_in[4];
    const float* gcn_bias  = (const float*)d_in[5];
    const float* w_ih[3] = {(const float*)d_in[6],  (const float*)d_in[10], (const float*)d_in[14]};
    const float* w_hh[3] = {(const float*)d_in[7],  (const float*)d_in[11], (const float*)d_in[15]};
    const float* b_ih[3] = {(const float*)d_in[8],  (const float*)d_in[12], (const float*)d_in[16]};
    const float* b_hh[3] = {(const float*)d_in[9],  (const float*)d_in[13], (const float*)d_in[17]};
    const float* lin_W = (const float*)d_in[18];
    const float* lin_b = (const float*)d_in[19];
    float* out = (float*)d_out;

    char* p = (char*)d_ws;
    auto alloc = [&](size_t bytes) {
        char* r = p;
        p += (bytes + 255) & ~(size_t)255;
        return r;
    };
    int*   deg    = (int*)alloc((size_t)NN * 4);   // ┐ contiguous: one memset
    int*   offs   = (int*)alloc((size_t)NN * 4);   // │
    int*   cursor = (int*)alloc((size_t)NN * 4);   // ┘
    int*   flagsA = (int*)alloc(128 * 4);          // ┐ contiguous: one memset
    float* acc2   = (float*)alloc(128 * 4);        // │
    int*   done2  = (int*)alloc(64 * 4);           // ┘
    float* dinv   = (float*)alloc((size_t)NN * 4);
    int*   eidx   = (int*)alloc((size_t)NE * 4);
    float* Bself  = (float*)alloc(256 * 4);
    float* hT     = (float*)alloc(2 * NB * 256 * 4);
    float* bias768 = (float*)alloc(3 * G3 * 4);
    unsigned int* h_ex = (unsigned int*)alloc((size_t)NB * 2 * 128 * 4);
    float* Ax     = (float*)alloc((size_t)NN * DOUT * 4);
    _Float16* xp16 = (_Float16*)alloc((size_t)NN * G3 * 2);

    _Float16* node16 = (_Float16*)alloc((size_t)NN * DOUT * 2);
    _Float16* yA16   = (_Float16*)alloc((size_t)NN * DOUT * 2);
    _Float16* x16    = (_Float16*)alloc((size_t)NN * DOUT * 2);
    _Float16* yB16   = x16;  // alias: x16 dead after Ax GEMM, yB16 live later
    _Float16* WA16   = (_Float16*)alloc((size_t)256 * 256 * 2);
    _Float16* wih16[3];
    for (int l = 0; l < 3; ++l) wih16[l] = (_Float16*)alloc((size_t)G3 * 256 * 2);

    // --- CSR build + weight conversions + bias fold ---
    hipMemsetAsync(deg, 0, (size_t)3 * NN * 4, stream);    // deg+offs+cursor
    hipMemsetAsync(flagsA, 0, 1280, stream);               // flags+acc2+done2
    k_count<<<NE / 256, 256, 0, stream>>>(ei, deg);
    k_scan_offs<<<1, 1024, 0, stream>>>(deg, offs, dinv);
    k_fill<<<NE / 256, 256, 0, stream>>>(ei, offs, cursor, eidx);
    k_bself<<<1, 256, 0, stream>>>(WB, Bself);
    k_bias_fold<<<9, 256, 0, stream>>>(b_ih[0], b_hh[0], b_ih[1], b_hh[1],
                                       b_ih[2], b_hh[2], bias768);
    k_cvt_all<<<4736, 256, 0, stream>>>(x, WA, w_ih[0], w_ih[1], w_ih[2],
                                        x16, WA16, wih16[0], wih16[1], wih16[2]);

    // --- GCN ---
    {
        dim3 g(NN / 128, 256 / 128);
        k_gemm16<false><<<g, 256, 0, stream>>>(x16, WA16, nullptr, Ax, NN, 256);
    }
    k_gcn<<<NN, 256, 0, stream>>>(Ax, WB, edge_attr, ei, eidx, offs, deg, dinv,
                                  Bself, gcn_bias, node16);

    // --- GRU x3 (layer 2 fuses pooling+linear+softmax) ---
    const _Float16* in16 = node16;
    _Float16* y16_outs[3] = {yA16, yB16, yA16};
    for (int l = 0; l < 3; ++l) {
        dim3 g(NN / 128, G3 / 128);
        k_gemm16<true><<<g, 256, 0, stream>>>(in16, wih16[l], bias768 + l * G3,
                                              xp16, NN, G3);
        k_gru_scan<<<NB * 2, 512, 0, stream>>>(xp16, w_hh[l], b_hh[l], y16_outs[l],
                                               hT, l, lin_W, lin_b, out,
                                               h_ex, flagsA, acc2, done2);
        in16 = y16_outs[l];
    }
}

// Round 4
// 1404.896 us; speedup vs baseline: 4.8680x; 4.8680x over previous
//
#include <hip/hip_runtime.h>
#include <math.h>

#define NN   16384      // total nodes
#define NE   262144     // edges (no self loops)
#define NB   64         // graphs
#define SEQT 256        // nodes per graph (= seq len)
#define DEP  64
#define DOUT 256        // = HID
#define G3   768        // 3*HID
#define GK   256        // GEMM K (always 256 here)
#define ECAP 32         // GCN edges staged per chunk

typedef _Float16 h2_t   __attribute__((ext_vector_type(2)));
typedef _Float16 f16x4  __attribute__((ext_vector_type(4)));
typedef _Float16 f16x8  __attribute__((ext_vector_type(8)));
typedef float    f32x4  __attribute__((ext_vector_type(4)));

static __device__ __forceinline__ h2_t pk(float a, float b) {
    return (h2_t)__builtin_amdgcn_cvt_pkrtz(a, b);
}

static __device__ __forceinline__ float fast_sigmoid(float v) {
    return __builtin_amdgcn_rcpf(1.f + __expf(-v));
}
static __device__ __forceinline__ float fast_tanh(float v) {
    return 1.f - 2.f * __builtin_amdgcn_rcpf(1.f + __expf(2.f * v));
}

// barrier with LDS-only drain (no vmcnt: in-flight global loads/stores cross)
static __device__ __forceinline__ void bar_lds() {
    asm volatile("s_waitcnt lgkmcnt(0)\n\ts_barrier" ::: "memory");
}

// ---------------------------------------------------------------------------
// degree / CSR build (deg zero-initialized by memset; holds RAW in-degree)
// ---------------------------------------------------------------------------
__global__ void k_count(const int* __restrict__ ei, int* deg) {
    int e = blockIdx.x * 256 + threadIdx.x;
    if (e < NE) atomicAdd(&deg[ei[NE + e]], 1);   // col = dst
}

__global__ __launch_bounds__(1024) void k_scan_offs(const int* __restrict__ deg,
                                                    int* __restrict__ offs,
                                                    float* __restrict__ dinv) {
    __shared__ int lds[1024];
    const int tid = threadIdx.x;
    const int v0 = tid * 16;
    int loc[16];
    int s = 0;
#pragma unroll
    for (int i = 0; i < 16; ++i) {
        int d = deg[v0 + i];                      // raw in-edges
        loc[i] = s;
        s += d;
        dinv[v0 + i] = rsqrtf((float)(d + 1));    // +1 self loop
    }
    lds[tid] = s;
    __syncthreads();
    for (int off = 1; off < 1024; off <<= 1) {
        int x = (tid >= off) ? lds[tid - off] : 0;
        __syncthreads();
        lds[tid] += x;
        __syncthreads();
    }
    int base = lds[tid] - s;                      // exclusive prefix of this thread
#pragma unroll
    for (int i = 0; i < 16; ++i) offs[v0 + i] = base + loc[i];
}

__global__ void k_fill(const int* __restrict__ ei, const int* __restrict__ offs,
                       int* cursor, int* __restrict__ eidx) {
    int e = blockIdx.x * 256 + threadIdx.x;
    if (e < NE) {
        int c = ei[NE + e];
        int pos = offs[c] + atomicAdd(&cursor[c], 1);
        eidx[pos] = e;
    }
}

__global__ void k_bself(const float* __restrict__ WB, float* Bself) {
    int f = threadIdx.x;                          // 256 threads
    float s = 0.f;
#pragma unroll
    for (int d = 0; d < DEP; ++d) s += WB[f * DEP + d];
    Bself[f] = s;
}

// bias fold: bias768[l][j] = b_ih[j] + (j<512 ? b_hh[j] : 0)   (b_hn stays
// separate: the reference scales it by r before adding)
__global__ void k_bias_fold(const float* __restrict__ bi0, const float* __restrict__ bh0,
                            const float* __restrict__ bi1, const float* __restrict__ bh1,
                            const float* __restrict__ bi2, const float* __restrict__ bh2,
                            float* __restrict__ o) {
    int j = blockIdx.x * 256 + threadIdx.x;       // 9 blocks x 256 = 2304
    int l = j / G3, r = j % G3;
    const float* bi = (l == 0) ? bi0 : (l == 1) ? bi1 : bi2;
    const float* bh = (l == 0) ? bh0 : (l == 1) ? bh1 : bh2;
    o[j] = bi[r] + (r < 512 ? bh[r] : 0.f);
}

// ---------------------------------------------------------------------------
// one fused fp32->f16 conversion over all 5 regions
// ---------------------------------------------------------------------------
__global__ void k_cvt_all(const float* __restrict__ x,  const float* __restrict__ wa,
                          const float* __restrict__ w0, const float* __restrict__ w1,
                          const float* __restrict__ w2,
                          _Float16* __restrict__ xo,  _Float16* __restrict__ wao,
                          _Float16* __restrict__ w0o, _Float16* __restrict__ w1o,
                          _Float16* __restrict__ w2o) {
    size_t i = ((size_t)blockIdx.x * 256 + threadIdx.x) * 4;
    const size_t B0 = 4194304, B1 = B0 + 65536, B2 = B1 + 196608, B3 = B2 + 196608;
    const float* in; _Float16* out; size_t off;
    if      (i < B0) { in = x;  out = xo;  off = i; }
    else if (i < B1) { in = wa; out = wao; off = i - B0; }
    else if (i < B2) { in = w0; out = w0o; off = i - B1; }
    else if (i < B3) { in = w1; out = w1o; off = i - B2; }
    else             { in = w2; out = w2o; off = i - B3; }
    float4 v = *(const float4*)(in + off);
    *(h2_t*)(out + off)     = pk(v.x, v.y);
    *(h2_t*)(out + off + 2) = pk(v.z, v.w);
}

// ---------------------------------------------------------------------------
// MFMA f16 GEMM: C[M,N] = A16[M,256] @ B16[N,256]^T (+ bias).
// F16OUT: store f16 (used for xp); else fp32 (used for Ax).
// ---------------------------------------------------------------------------
template <bool F16OUT>
__global__ __launch_bounds__(256) void k_gemm16(const _Float16* __restrict__ A16,
                                                const _Float16* __restrict__ B16,
                                                const float* __restrict__ bias,
                                                void* __restrict__ Cout,
                                                int M, int N) {
    const int tid  = threadIdx.x;
    const int lane = tid & 63;
    const int wv   = tid >> 6;
    const int m0   = blockIdx.x * 128 + wv * 32;
    const int n0   = blockIdx.y * 128;
    const int ml   = lane & 15;
    const int quad = lane >> 4;

    const _Float16* ap0 = A16 + (size_t)(m0 + ml) * GK + quad * 8;
    const _Float16* ap1 = ap0 + (size_t)16 * GK;
    const _Float16* bp0 = B16 + (size_t)(n0 + ml) * GK + quad * 8;

    f32x4 acc[2][8];
#pragma unroll
    for (int i = 0; i < 2; ++i)
#pragma unroll
        for (int j = 0; j < 8; ++j) acc[i][j] = (f32x4){0.f, 0.f, 0.f, 0.f};

#pragma unroll 2
    for (int k0 = 0; k0 < GK; k0 += 32) {
        f16x8 a0 = *(const f16x8*)(ap0 + k0);
        f16x8 a1 = *(const f16x8*)(ap1 + k0);
#pragma unroll
        for (int nf = 0; nf < 8; ++nf) {
            f16x8 bf = *(const f16x8*)(bp0 + (size_t)nf * 16 * GK + k0);
            acc[0][nf] = __builtin_amdgcn_mfma_f32_16x16x32_f16(a0, bf, acc[0][nf], 0, 0, 0);
            acc[1][nf] = __builtin_amdgcn_mfma_f32_16x16x32_f16(a1, bf, acc[1][nf], 0, 0, 0);
        }
    }

#pragma unroll
    for (int mf = 0; mf < 2; ++mf)
#pragma unroll
        for (int nf = 0; nf < 8; ++nf) {
            const int col = n0 + nf * 16 + ml;
            const float bv = bias ? bias[col] : 0.f;
#pragma unroll
            for (int r = 0; r < 4; ++r) {
                const int row = m0 + mf * 16 + quad * 4 + r;
                float v = acc[mf][nf][r] + bv;
                if (F16OUT)
                    ((_Float16*)Cout)[(size_t)row * N + col] = (_Float16)v;
                else
                    ((float*)Cout)[(size_t)row * N + col] = v;
            }
        }
}

// ---------------------------------------------------------------------------
// GCN gather v2: chunked LDS staging, fast_tanh.
// ---------------------------------------------------------------------------
__global__ __launch_bounds__(256) void k_gcn(const float* __restrict__ Ax,
                                             const float* __restrict__ WB,
                                             const float* __restrict__ edge_attr,
                                             const int* __restrict__ ei,
                                             const int* __restrict__ eidx,
                                             const int* __restrict__ offs,
                                             const int* __restrict__ deg,
                                             const float* __restrict__ dinv,
                                             const float* __restrict__ Bself,
                                             const float* __restrict__ gcn_bias,
                                             _Float16* __restrict__ node16) {
    const int v = blockIdx.x;
    const int f = threadIdx.x;

    float wb[64];
#pragma unroll
    for (int d4 = 0; d4 < 16; ++d4) {
        float4 t = *(const float4*)&WB[f * DEP + d4 * 4];
        wb[d4 * 4 + 0] = t.x; wb[d4 * 4 + 1] = t.y;
        wb[d4 * 4 + 2] = t.z; wb[d4 * 4 + 3] = t.w;
    }

    __shared__ float ea_s[ECAP * 64];
    __shared__ int   es_s[ECAP];
    __shared__ int   src_s[ECAP];
    __shared__ float nrm_s[ECAP];

    const int   base = offs[v];
    const int   cnt  = deg[v];                   // raw in-edges
    const float dv   = dinv[v];
    float acc = 0.f;

    for (int c0 = 0; c0 < cnt; c0 += ECAP) {
        const int n = min(ECAP, cnt - c0);
        if (f < n) {
            int e = eidx[base + c0 + f];
            es_s[f] = e;
            int s = ei[e];
            src_s[f] = s;
            nrm_s[f] = dinv[s] * dv;
        }
        __syncthreads();
        for (int idx = f; idx < n * 64; idx += 256) {
            int el = idx >> 6, d = idx & 63;
            ea_s[idx] = edge_attr[(size_t)es_s[el] * DEP + d];
        }
        __syncthreads();
        for (int i = 0; i < n; ++i) {
            float ax = Ax[(size_t)src_s[i] * DOUT + f];   // issued early
            float be = 0.f;
#pragma unroll
            for (int d = 0; d < 64; ++d) be = fmaf(wb[d], ea_s[i * 64 + d], be);
            acc = fmaf(nrm_s[i], fast_tanh(ax * be), acc);
        }
        __syncthreads();                          // before chunk overwrite
    }
    // self loop: norm = dinv^2, Be = rowsum(WB)
    acc += dv * dv * fast_tanh(Ax[(size_t)v * DOUT + f] * Bself[f]);
    float nv = fast_tanh(acc / (float)(cnt + 1) + gcn_bias[f]);
    node16[(size_t)v * DOUT + f] = (_Float16)nv;
}

// ---------------------------------------------------------------------------
// GRU scan v12: v10 structure + FULLY IN-REGISTER GATES (no gh LDS trip).
//
// v11 post-mortem (REVERTED): pairwise row-split across 2 blocks required a
// per-step cross-CU flag handshake through agent-scope atomics; measured
// ~7 us/step (~20k cyc) -- 6x regression.  Cross-block per-step sync is
// dead; all h-exchange must stay inside one workgroup.
//
// v12 observation: with v10's A-row permutation (row = g*256 + 32*wv +
// (lr&31), lr = rb*16+m), the C-fragment layout (col = lane&15 -- all 16
// cols identical since B cols are identical; row = quad*4 + reg) already
// places gh[g] for hidden unit j = 32*wv + 16*(m>>3) + 4*quad + (m&3) in
// register C[2g + (m>>3)][m&3] of that very lane.  So gates can be computed
// entirely in-register: 7 loop-invariant-predicate cndmasks per gate
// replace {6x ds_write + lgkmcnt(0) + 3x ds_read + addressing}.  Two lanes
// per j (m&4 dup) compute identical gates; (m&4)==0 lanes are unique
// writers of h16/y16.  Values are bit-identical to v10's LDS round-trip.
// One barrier per step remains (publish h(t+1)).
// ---------------------------------------------------------------------------
__global__ __launch_bounds__(512, 2) void k_gru_scan(const _Float16* __restrict__ xp16,
                                                     const float* __restrict__ w_hh,
                                                     const float* __restrict__ b_hh,
                                                     _Float16* __restrict__ y16,
                                                     float* __restrict__ hT_all,
                                                     int layer,
                                                     const float* __restrict__ lin_W,
                                                     const float* __restrict__ lin_b,
                                                     float* __restrict__ out) {
    const int tid  = threadIdx.x;
    const int b    = blockIdx.x;                 // graph
    const int lane = tid & 63;
    const int wv   = tid >> 6;                   // wave 0..7
    const int m    = lane & 15;                  // A-frag row within 16
    const int quad = lane >> 4;                  // 0..3 (k-subgroup)
    const int p    = (m >> 3) & 1;               // frag-half select
    const int rsel = m & 3;                      // C-reg select
    const int j    = wv * 32 + p * 16 + quad * 4 + rsel;  // lane's hidden unit
    const bool wr  = (m & 4) == 0;               // unique writer per j (2 lanes/j)

    // --- weights -> A-fragments (one-time global read, fp32 -> f16) ---
    // local row lr = rb*16 + m; global w_hh row = 256*(lr/32) + 32*wv + lr%32
    // => frag pair (2g, 2g+1) holds gate g's rows for this wave's 32 j's.
    f16x8 A[6][8];
#pragma unroll
    for (int rb = 0; rb < 6; ++rb) {
        const int lr  = rb * 16 + m;
        const int row = ((lr >> 5) << 8) + wv * 32 + (lr & 31);
#pragma unroll
        for (int kt = 0; kt < 8; ++kt) {
            const float* wp = w_hh + (size_t)row * 256 + kt * 32 + quad * 8;
            float4 a0 = *(const float4*)wp;
            float4 a1 = *(const float4*)(wp + 4);
            union { f16x8 v; h2_t h[4]; } u;
            u.h[0] = pk(a0.x, a0.y); u.h[1] = pk(a0.z, a0.w);
            u.h[2] = pk(a1.x, a1.y); u.h[3] = pk(a1.z, a1.w);
            A[rb][kt] = u.v;
        }
    }

    const float bhn = b_hh[512 + j];             // n-gate hidden bias (r/z folded)

    __shared__ _Float16 h16[2][256];             // h(t) f16, double-buffered
    __shared__ float    pool[1280];              // layer-2 epilogue only
    __shared__ float    red[512];

    float h_old = 0.f;                           // this lane's h[j]
    if (tid < 256) h16[0][tid] = (_Float16)0.f;
    __syncthreads();

    const _Float16* xpb  = xp16 + (size_t)b * SEQT * G3;
    _Float16*       yb16 = y16  + (size_t)b * SEQT * DOUT;

    float mx = -1e30f, sm = 0.f;                 // layer-2 pooling accum

    // prefetch xp(0) (loop-carried registers; re-issued each step for t+1)
    _Float16 pxr = xpb[j], pxz = xpb[256 + j], pxn = xpb[512 + j];

    for (int t = 0; t < SEQT; ++t) {
        // consume this step's prefetched xp (loads issued one step ago)
        const float xr = (float)pxr;
        const float xz = (float)pxz;
        const float xn = (float)pxn;
        // issue NEXT step's xp loads now -- they ride out the whole MFMA
        // phase + barrier (bar_lds has no vmcnt drain).  t=255 reads the
        // workspace tail: in-bounds, values unused.
        {
            const _Float16* xq = xpb + (size_t)(t + 1) * G3 + j;
            pxr = xq[0]; pxz = xq[256]; pxn = xq[512];
        }

        // k-outer MFMA: straight-line; compiler hoists the 8 ds_read_b128
        const _Float16* hcur = h16[t & 1];
        f32x4 C[6];
#pragma unroll
        for (int rb = 0; rb < 6; ++rb) C[rb] = (f32x4){0.f, 0.f, 0.f, 0.f};

#pragma unroll
        for (int kt = 0; kt < 8; ++kt) {
            union { f16x8 v; float4 f; } Bk;
            Bk.f = *(const float4*)&hcur[kt * 32 + quad * 8];
#pragma unroll
            for (int rb = 0; rb < 6; ++rb)
                C[rb] = __builtin_amdgcn_mfma_f32_16x16x32_f16(A[rb][kt], Bk.v, C[rb], 0, 0, 0);
        }

        // in-register gh extraction: value for this lane's j sits at
        // C[2g + p][rsel] (predicates rsel&1, rsel&2, p are loop-invariant)
        float gh[3];
#pragma unroll
        for (int g = 0; g < 3; ++g) {
            const float lo01 = (rsel & 1) ? C[2 * g][1] : C[2 * g][0];
            const float lo23 = (rsel & 1) ? C[2 * g][3] : C[2 * g][2];
            const float lo   = (rsel & 2) ? lo23 : lo01;
            const float hi01 = (rsel & 1) ? C[2 * g + 1][1] : C[2 * g + 1][0];
            const float hi23 = (rsel & 1) ? C[2 * g + 1][3] : C[2 * g + 1][2];
            const float hi   = (rsel & 2) ? hi23 : hi01;
            gh[g] = p ? hi : lo;
        }

        const float r  = fast_sigmoid(xr + gh[0]);
        const float z  = fast_sigmoid(xz + gh[1]);
        const float n  = fast_tanh(xn + r * (gh[2] + bhn));
        const float hn = n + z * (h_old - n);
        h_old = hn;
        if (wr) {
            h16[(t & 1) ^ 1][j] = (_Float16)hn;  // next step's buffer
            if (layer < 2) {
                yb16[(size_t)t * DOUT + j] = (_Float16)hn;
                if (t == SEQT - 1) hT_all[layer * NB * 256 + b * 256 + j] = hn;
            }
        }
        if (layer == 2) { mx = fmaxf(mx, hn); sm += hn; }

        bar_lds();                               // the ONLY per-step barrier
    }

    if (layer == 2) {
        // --- fused pooling + linear + softmax ---
        if (wr) {
            pool[j]        = hT_all[b * 256 + j];               // layer-0 hT
            pool[256 + j]  = hT_all[NB * 256 + b * 256 + j];    // layer-1 hT
            pool[512 + j]  = h_old;                             // layer-2 hT
            pool[768 + j]  = mx;
            pool[1024 + j] = sm * (1.f / 256.f);
        }
        __syncthreads();
        if (tid < 256) {
            float p0 = 0.f, p1 = 0.f;
            for (int i = tid; i < 1280; i += 256) {
                float pv = pool[i];
                p0 = fmaf(lin_W[i], pv, p0);
                p1 = fmaf(lin_W[1280 + i], pv, p1);
            }
            red[tid] = p0; red[256 + tid] = p1;
        }
        __syncthreads();
        if (tid == 0) {
            float l0 = lin_b[0], l1 = lin_b[1];
            for (int i = 0; i < 256; ++i) { l0 += red[i]; l1 += red[256 + i]; }
            float m2 = fmaxf(l0, l1);
            float e0 = __expf(l0 - m2), e1 = __expf(l1 - m2);
            float s = e0 + e1;
            out[b * 2 + 0] = e0 / s;
            out[b * 2 + 1] = e1 / s;
        }
    }
}

// ---------------------------------------------------------------------------
extern "C" void kernel_launch(void* const* d_in, const int* in_sizes, int n_in,
                              void* d_out, int out_size, void* d_ws, size_t ws_size,
                              hipStream_t stream) {
    const float* x         = (const float*)d_in[0];
    const float* edge_attr = (const float*)d_in[1];
    const int*   ei        = (const int*)d_in[2];
    const float* WA        = (const float*)d_in[3];
    const float* WB        = (const float*)d_in[4];
    const float* gcn_bias  = (const float*)d_in[5];
    const float* w_ih[3] = {(const float*)d_in[6],  (const float*)d_in[10], (const float*)d_in[14]};
    const float* w_hh[3] = {(const float*)d_in[7],  (const float*)d_in[11], (const float*)d_in[15]};
    const float* b_ih[3] = {(const float*)d_in[8],  (const float*)d_in[12], (const float*)d_in[16]};
    const float* b_hh[3] = {(const float*)d_in[9],  (const float*)d_in[13], (const float*)d_in[17]};
    const float* lin_W = (const float*)d_in[18];
    const float* lin_b = (const float*)d_in[19];
    float* out = (float*)d_out;

    char* p = (char*)d_ws;
    auto alloc = [&](size_t bytes) {
        char* r = p;
        p += (bytes + 255) & ~(size_t)255;
        return r;
    };
    int*   deg    = (int*)alloc((size_t)NN * 4);   // ┐ contiguous: one memset
    int*   offs   = (int*)alloc((size_t)NN * 4);   // │
    int*   cursor = (int*)alloc((size_t)NN * 4);   // ┘
    float* dinv   = (float*)alloc((size_t)NN * 4);
    int*   eidx   = (int*)alloc((size_t)NE * 4);
    float* Bself  = (float*)alloc(256 * 4);
    float* hT     = (float*)alloc(2 * NB * 256 * 4);
    float* bias768 = (float*)alloc(3 * G3 * 4);
    float* Ax     = (float*)alloc((size_t)NN * DOUT * 4);
    _Float16* xp16 = (_Float16*)alloc((size_t)NN * G3 * 2);

    _Float16* node16 = (_Float16*)alloc((size_t)NN * DOUT * 2);
    _Float16* yA16   = (_Float16*)alloc((size_t)NN * DOUT * 2);
    _Float16* x16    = (_Float16*)alloc((size_t)NN * DOUT * 2);
    _Float16* yB16   = x16;  // alias: x16 dead after Ax GEMM, yB16 live later
    _Float16* WA16   = (_Float16*)alloc((size_t)256 * 256 * 2);
    _Float16* wih16[3];
    for (int l = 0; l < 3; ++l) wih16[l] = (_Float16*)alloc((size_t)G3 * 256 * 2);

    // --- CSR build + weight conversions + bias fold ---
    hipMemsetAsync(deg, 0, (size_t)3 * NN * 4, stream);    // deg+offs+cursor
    k_count<<<NE / 256, 256, 0, stream>>>(ei, deg);
    k_scan_offs<<<1, 1024, 0, stream>>>(deg, offs, dinv);
    k_fill<<<NE / 256, 256, 0, stream>>>(ei, offs, cursor, eidx);
    k_bself<<<1, 256, 0, stream>>>(WB, Bself);
    k_bias_fold<<<9, 256, 0, stream>>>(b_ih[0], b_hh[0], b_ih[1], b_hh[1],
                                       b_ih[2], b_hh[2], bias768);
    k_cvt_all<<<4736, 256, 0, stream>>>(x, WA, w_ih[0], w_ih[1], w_ih[2],
                                        x16, WA16, wih16[0], wih16[1], wih16[2]);

    // --- GCN ---
    {
        dim3 g(NN / 128, 256 / 128);
        k_gemm16<false><<<g, 256, 0, stream>>>(x16, WA16, nullptr, Ax, NN, 256);
    }
    k_gcn<<<NN, 256, 0, stream>>>(Ax, WB, edge_attr, ei, eidx, offs, deg, dinv,
                                  Bself, gcn_bias, node16);

    // --- GRU x3 (layer 2 fuses pooling+linear+softmax) ---
    const _Float16* in16 = node16;
    _Float16* y16_outs[3] = {yA16, yB16, yA16};
    for (int l = 0; l < 3; ++l) {
        dim3 g(NN / 128, G3 / 128);
        k_gemm16<true><<<g, 256, 0, stream>>>(in16, wih16[l], bias768 + l * G3,
                                              xp16, NN, G3);
        k_gru_scan<<<NB, 512, 0, stream>>>(xp16, w_hh[l], b_hh[l], y16_outs[l],
                                           hT, l, lin_W, lin_b, out);
        in16 = y16_outs[l];
    }
}

// Round 5
// 1260.667 us; speedup vs baseline: 5.4249x; 1.1144x over previous
//
#include <hip/hip_runtime.h>
#include <math.h>

#define NN   16384      // total nodes
#define NE   262144     // edges (no self loops)
#define NB   64         // graphs
#define SEQT 256        // nodes per graph (= seq len)
#define DEP  64
#define DOUT 256        // = HID
#define G3   768        // 3*HID
#define ECAP 64         // GCN edges staged per chunk

typedef _Float16 h2_t   __attribute__((ext_vector_type(2)));
typedef _Float16 f16x4  __attribute__((ext_vector_type(4)));
typedef _Float16 f16x8  __attribute__((ext_vector_type(8)));
typedef float    f32x4  __attribute__((ext_vector_type(4)));

static __device__ __forceinline__ h2_t pk(float a, float b) {
    return (h2_t)__builtin_amdgcn_cvt_pkrtz(a, b);
}

static __device__ __forceinline__ float fast_sigmoid(float v) {
    return __builtin_amdgcn_rcpf(1.f + __expf(-v));
}
static __device__ __forceinline__ float fast_tanh(float v) {
    return 1.f - 2.f * __builtin_amdgcn_rcpf(1.f + __expf(2.f * v));
}

// barrier with LDS-only drain (no vmcnt: in-flight global loads/stores cross)
static __device__ __forceinline__ void bar_lds() {
    asm volatile("s_waitcnt lgkmcnt(0)\n\ts_barrier" ::: "memory");
}

// ---------------------------------------------------------------------------
// degree / CSR build (deg zero-initialized by memset; holds RAW in-degree)
// ---------------------------------------------------------------------------
__global__ void k_count(const int* __restrict__ ei, int* deg) {
    int e = blockIdx.x * 256 + threadIdx.x;
    if (e < NE) atomicAdd(&deg[ei[NE + e]], 1);   // col = dst
}

__global__ __launch_bounds__(1024) void k_scan_offs(const int* __restrict__ deg,
                                                    int* __restrict__ offs,
                                                    float* __restrict__ dinv) {
    __shared__ int lds[1024];
    const int tid = threadIdx.x;
    const int v0 = tid * 16;
    int loc[16];
    int s = 0;
#pragma unroll
    for (int i = 0; i < 16; ++i) {
        int d = deg[v0 + i];                      // raw in-edges
        loc[i] = s;
        s += d;
        dinv[v0 + i] = rsqrtf((float)(d + 1));    // +1 self loop
    }
    lds[tid] = s;
    __syncthreads();
    for (int off = 1; off < 1024; off <<= 1) {
        int x = (tid >= off) ? lds[tid - off] : 0;
        __syncthreads();
        lds[tid] += x;
        __syncthreads();
    }
    int base = lds[tid] - s;                      // exclusive prefix of this thread
#pragma unroll
    for (int i = 0; i < 16; ++i) offs[v0 + i] = base + loc[i];
}

__global__ void k_fill(const int* __restrict__ ei, const int* __restrict__ offs,
                       int* cursor, int* __restrict__ eidx) {
    int e = blockIdx.x * 256 + threadIdx.x;
    if (e < NE) {
        int c = ei[NE + e];
        int pos = offs[c] + atomicAdd(&cursor[c], 1);
        eidx[pos] = e;
    }
}

__global__ void k_bself(const float* __restrict__ WB, float* Bself) {
    int f = threadIdx.x;                          // 256 threads
    float s = 0.f;
#pragma unroll
    for (int d = 0; d < DEP; ++d) s += WB[f * DEP + d];
    Bself[f] = s;
}

// bias fold: bias768[l][j] = b_ih[j] + (j<512 ? b_hh[j] : 0)   (b_hn stays
// separate: the reference scales it by r before adding)
__global__ void k_bias_fold(const float* __restrict__ bi0, const float* __restrict__ bh0,
                            const float* __restrict__ bi1, const float* __restrict__ bh1,
                            const float* __restrict__ bi2, const float* __restrict__ bh2,
                            float* __restrict__ o) {
    int j = blockIdx.x * 256 + threadIdx.x;       // 9 blocks x 256 = 2304
    int l = j / G3, r = j % G3;
    const float* bi = (l == 0) ? bi0 : (l == 1) ? bi1 : bi2;
    const float* bh = (l == 0) ? bh0 : (l == 1) ? bh1 : bh2;
    o[j] = bi[r] + (r < 512 ? bh[r] : 0.f);
}

// ---------------------------------------------------------------------------
// one fused fp32->f16 conversion over all 7 regions
// (x, WA, w_ih0/1/2, edge_attr, WB)
// ---------------------------------------------------------------------------
__global__ void k_cvt_all(const float* __restrict__ x,  const float* __restrict__ wa,
                          const float* __restrict__ w0, const float* __restrict__ w1,
                          const float* __restrict__ w2, const float* __restrict__ ea,
                          const float* __restrict__ wb,
                          _Float16* __restrict__ xo,  _Float16* __restrict__ wao,
                          _Float16* __restrict__ w0o, _Float16* __restrict__ w1o,
                          _Float16* __restrict__ w2o, _Float16* __restrict__ eao,
                          _Float16* __restrict__ wbo) {
    size_t i = ((size_t)blockIdx.x * 256 + threadIdx.x) * 4;
    const size_t B0 = 4194304;                  // x: NN*256
    const size_t B1 = B0 + 65536;               // WA: 256*256
    const size_t B2 = B1 + 196608;              // w_ih0: 768*256
    const size_t B3 = B2 + 196608;              // w_ih1
    const size_t B4 = B3 + 196608;              // w_ih2
    const size_t B5 = B4 + 16777216;            // edge_attr: NE*64
    const float* in; _Float16* out; size_t off;
    if      (i < B0) { in = x;  out = xo;  off = i; }
    else if (i < B1) { in = wa; out = wao; off = i - B0; }
    else if (i < B2) { in = w0; out = w0o; off = i - B1; }
    else if (i < B3) { in = w1; out = w1o; off = i - B2; }
    else if (i < B4) { in = w2; out = w2o; off = i - B3; }
    else if (i < B5) { in = ea; out = eao; off = i - B4; }
    else             { in = wb; out = wbo; off = i - B5; }
    float4 v = *(const float4*)(in + off);
    *(h2_t*)(out + off)     = pk(v.x, v.y);
    *(h2_t*)(out + off + 2) = pk(v.z, v.w);
}

// ---------------------------------------------------------------------------
// MFMA f16 GEMM: C[M,N] = A16[M,K] @ B16[N,K]^T (+ bias).
// K: 256 (node GEMMs) or 64 (edge Be GEMM). F16OUT: f16 store, else fp32.
// ---------------------------------------------------------------------------
template <int K, bool F16OUT>
__global__ __launch_bounds__(256) void k_gemm16(const _Float16* __restrict__ A16,
                                                const _Float16* __restrict__ B16,
                                                const float* __restrict__ bias,
                                                void* __restrict__ Cout,
                                                int M, int N) {
    const int tid  = threadIdx.x;
    const int lane = tid & 63;
    const int wv   = tid >> 6;
    const int m0   = blockIdx.x * 128 + wv * 32;
    const int n0   = blockIdx.y * 128;
    const int ml   = lane & 15;
    const int quad = lane >> 4;

    const _Float16* ap0 = A16 + (size_t)(m0 + ml) * K + quad * 8;
    const _Float16* ap1 = ap0 + (size_t)16 * K;
    const _Float16* bp0 = B16 + (size_t)(n0 + ml) * K + quad * 8;

    f32x4 acc[2][8];
#pragma unroll
    for (int i = 0; i < 2; ++i)
#pragma unroll
        for (int j = 0; j < 8; ++j) acc[i][j] = (f32x4){0.f, 0.f, 0.f, 0.f};

#pragma unroll 2
    for (int k0 = 0; k0 < K; k0 += 32) {
        f16x8 a0 = *(const f16x8*)(ap0 + k0);
        f16x8 a1 = *(const f16x8*)(ap1 + k0);
#pragma unroll
        for (int nf = 0; nf < 8; ++nf) {
            f16x8 bf = *(const f16x8*)(bp0 + (size_t)nf * 16 * K + k0);
            acc[0][nf] = __builtin_amdgcn_mfma_f32_16x16x32_f16(a0, bf, acc[0][nf], 0, 0, 0);
            acc[1][nf] = __builtin_amdgcn_mfma_f32_16x16x32_f16(a1, bf, acc[1][nf], 0, 0, 0);
        }
    }

#pragma unroll
    for (int mf = 0; mf < 2; ++mf)
#pragma unroll
        for (int nf = 0; nf < 8; ++nf) {
            const int col = n0 + nf * 16 + ml;
            const float bv = bias ? bias[col] : 0.f;
#pragma unroll
            for (int r = 0; r < 4; ++r) {
                const int row = m0 + mf * 16 + quad * 4 + r;
                float v = acc[mf][nf][r] + bv;
                if (F16OUT)
                    ((_Float16*)Cout)[(size_t)row * N + col] = (_Float16)v;
                else
                    ((float*)Cout)[(size_t)row * N + col] = v;
            }
        }
}

// ---------------------------------------------------------------------------
// GCN gather v3: Be precomputed by MFMA GEMM (was 64 scalar fp32 FMAs per
// edge-feature on the VALU = 8.6 GFLOP at 0% MfmaUtil -> 320 us).  Now the
// edge loop is two loads + tanh + fma per feature.  ea_s staging and the
// wb[64] register array are gone (ECAP up to 64, LDS < 1 KB).
// ---------------------------------------------------------------------------
__global__ __launch_bounds__(256) void k_gcn(const float* __restrict__ Ax,
                                             const _Float16* __restrict__ Be16,
                                             const int* __restrict__ ei,
                                             const int* __restrict__ eidx,
                                             const int* __restrict__ offs,
                                             const int* __restrict__ deg,
                                             const float* __restrict__ dinv,
                                             const float* __restrict__ Bself,
                                             const float* __restrict__ gcn_bias,
                                             _Float16* __restrict__ node16) {
    const int v = blockIdx.x;
    const int f = threadIdx.x;

    __shared__ int   es_s[ECAP];
    __shared__ int   src_s[ECAP];
    __shared__ float nrm_s[ECAP];

    const int   base = offs[v];
    const int   cnt  = deg[v];                   // raw in-edges
    const float dv   = dinv[v];
    float acc = 0.f;

    for (int c0 = 0; c0 < cnt; c0 += ECAP) {
        const int n = min(ECAP, cnt - c0);
        if (f < n) {
            int e = eidx[base + c0 + f];
            es_s[f] = e;
            int s = ei[e];
            src_s[f] = s;
            nrm_s[f] = dinv[s] * dv;
        }
        __syncthreads();
#pragma unroll 4
        for (int i = 0; i < n; ++i) {
            float ax = Ax[(size_t)src_s[i] * DOUT + f];
            float be = (float)Be16[(size_t)es_s[i] * DOUT + f];
            acc = fmaf(nrm_s[i], fast_tanh(ax * be), acc);
        }
        __syncthreads();                          // before chunk overwrite
    }
    // self loop: norm = dinv^2, Be = rowsum(WB)
    acc += dv * dv * fast_tanh(Ax[(size_t)v * DOUT + f] * Bself[f]);
    float nv = fast_tanh(acc / (float)(cnt + 1) + gcn_bias[f]);
    node16[(size_t)v * DOUT + f] = (_Float16)nv;
}

// ---------------------------------------------------------------------------
// GRU scan v12: v10 structure + FULLY IN-REGISTER GATES (no gh LDS trip).
// (unchanged from R4 -- verified 1405 us total, scan < 320 us)
// ---------------------------------------------------------------------------
__global__ __launch_bounds__(512, 2) void k_gru_scan(const _Float16* __restrict__ xp16,
                                                     const float* __restrict__ w_hh,
                                                     const float* __restrict__ b_hh,
                                                     _Float16* __restrict__ y16,
                                                     float* __restrict__ hT_all,
                                                     int layer,
                                                     const float* __restrict__ lin_W,
                                                     const float* __restrict__ lin_b,
                                                     float* __restrict__ out) {
    const int tid  = threadIdx.x;
    const int b    = blockIdx.x;                 // graph
    const int lane = tid & 63;
    const int wv   = tid >> 6;                   // wave 0..7
    const int m    = lane & 15;                  // A-frag row within 16
    const int quad = lane >> 4;                  // 0..3 (k-subgroup)
    const int p    = (m >> 3) & 1;               // frag-half select
    const int rsel = m & 3;                      // C-reg select
    const int j    = wv * 32 + p * 16 + quad * 4 + rsel;  // lane's hidden unit
    const bool wr  = (m & 4) == 0;               // unique writer per j (2 lanes/j)

    // --- weights -> A-fragments (one-time global read, fp32 -> f16) ---
    // local row lr = rb*16 + m; global w_hh row = 256*(lr/32) + 32*wv + lr%32
    // => frag pair (2g, 2g+1) holds gate g's rows for this wave's 32 j's.
    f16x8 A[6][8];
#pragma unroll
    for (int rb = 0; rb < 6; ++rb) {
        const int lr  = rb * 16 + m;
        const int row = ((lr >> 5) << 8) + wv * 32 + (lr & 31);
#pragma unroll
        for (int kt = 0; kt < 8; ++kt) {
            const float* wp = w_hh + (size_t)row * 256 + kt * 32 + quad * 8;
            float4 a0 = *(const float4*)wp;
            float4 a1 = *(const float4*)(wp + 4);
            union { f16x8 v; h2_t h[4]; } u;
            u.h[0] = pk(a0.x, a0.y); u.h[1] = pk(a0.z, a0.w);
            u.h[2] = pk(a1.x, a1.y); u.h[3] = pk(a1.z, a1.w);
            A[rb][kt] = u.v;
        }
    }

    const float bhn = b_hh[512 + j];             // n-gate hidden bias (r/z folded)

    __shared__ _Float16 h16[2][256];             // h(t) f16, double-buffered
    __shared__ float    pool[1280];              // layer-2 epilogue only
    __shared__ float    red[512];

    float h_old = 0.f;                           // this lane's h[j]
    if (tid < 256) h16[0][tid] = (_Float16)0.f;
    __syncthreads();

    const _Float16* xpb  = xp16 + (size_t)b * SEQT * G3;
    _Float16*       yb16 = y16  + (size_t)b * SEQT * DOUT;

    float mx = -1e30f, sm = 0.f;                 // layer-2 pooling accum

    // prefetch xp(0) (loop-carried registers; re-issued each step for t+1)
    _Float16 pxr = xpb[j], pxz = xpb[256 + j], pxn = xpb[512 + j];

    for (int t = 0; t < SEQT; ++t) {
        // consume this step's prefetched xp (loads issued one step ago)
        const float xr = (float)pxr;
        const float xz = (float)pxz;
        const float xn = (float)pxn;
        // issue NEXT step's xp loads now -- they ride out the whole MFMA
        // phase + barrier (bar_lds has no vmcnt drain).  t=255 reads the
        // workspace tail: in-bounds, values unused.
        {
            const _Float16* xq = xpb + (size_t)(t + 1) * G3 + j;
            pxr = xq[0]; pxz = xq[256]; pxn = xq[512];
        }

        // k-outer MFMA: straight-line; compiler hoists the 8 ds_read_b128
        const _Float16* hcur = h16[t & 1];
        f32x4 C[6];
#pragma unroll
        for (int rb = 0; rb < 6; ++rb) C[rb] = (f32x4){0.f, 0.f, 0.f, 0.f};

#pragma unroll
        for (int kt = 0; kt < 8; ++kt) {
            union { f16x8 v; float4 f; } Bk;
            Bk.f = *(const float4*)&hcur[kt * 32 + quad * 8];
#pragma unroll
            for (int rb = 0; rb < 6; ++rb)
                C[rb] = __builtin_amdgcn_mfma_f32_16x16x32_f16(A[rb][kt], Bk.v, C[rb], 0, 0, 0);
        }

        // in-register gh extraction: value for this lane's j sits at
        // C[2g + p][rsel] (predicates rsel&1, rsel&2, p are loop-invariant)
        float gh[3];
#pragma unroll
        for (int g = 0; g < 3; ++g) {
            const float lo01 = (rsel & 1) ? C[2 * g][1] : C[2 * g][0];
            const float lo23 = (rsel & 1) ? C[2 * g][3] : C[2 * g][2];
            const float lo   = (rsel & 2) ? lo23 : lo01;
            const float hi01 = (rsel & 1) ? C[2 * g + 1][1] : C[2 * g + 1][0];
            const float hi23 = (rsel & 1) ? C[2 * g + 1][3] : C[2 * g + 1][2];
            const float hi   = (rsel & 2) ? hi23 : hi01;
            gh[g] = p ? hi : lo;
        }

        const float r  = fast_sigmoid(xr + gh[0]);
        const float z  = fast_sigmoid(xz + gh[1]);
        const float n  = fast_tanh(xn + r * (gh[2] + bhn));
        const float hn = n + z * (h_old - n);
        h_old = hn;
        if (wr) {
            h16[(t & 1) ^ 1][j] = (_Float16)hn;  // next step's buffer
            if (layer < 2) {
                yb16[(size_t)t * DOUT + j] = (_Float16)hn;
                if (t == SEQT - 1) hT_all[layer * NB * 256 + b * 256 + j] = hn;
            }
        }
        if (layer == 2) { mx = fmaxf(mx, hn); sm += hn; }

        bar_lds();                               // the ONLY per-step barrier
    }

    if (layer == 2) {
        // --- fused pooling + linear + softmax ---
        if (wr) {
            pool[j]        = hT_all[b * 256 + j];               // layer-0 hT
            pool[256 + j]  = hT_all[NB * 256 + b * 256 + j];    // layer-1 hT
            pool[512 + j]  = h_old;                             // layer-2 hT
            pool[768 + j]  = mx;
            pool[1024 + j] = sm * (1.f / 256.f);
        }
        __syncthreads();
        if (tid < 256) {
            float p0 = 0.f, p1 = 0.f;
            for (int i = tid; i < 1280; i += 256) {
                float pv = pool[i];
                p0 = fmaf(lin_W[i], pv, p0);
                p1 = fmaf(lin_W[1280 + i], pv, p1);
            }
            red[tid] = p0; red[256 + tid] = p1;
        }
        __syncthreads();
        if (tid == 0) {
            float l0 = lin_b[0], l1 = lin_b[1];
            for (int i = 0; i < 256; ++i) { l0 += red[i]; l1 += red[256 + i]; }
            float m2 = fmaxf(l0, l1);
            float e0 = __expf(l0 - m2), e1 = __expf(l1 - m2);
            float s = e0 + e1;
            out[b * 2 + 0] = e0 / s;
            out[b * 2 + 1] = e1 / s;
        }
    }
}

// ---------------------------------------------------------------------------
extern "C" void kernel_launch(void* const* d_in, const int* in_sizes, int n_in,
                              void* d_out, int out_size, void* d_ws, size_t ws_size,
                              hipStream_t stream) {
    const float* x         = (const float*)d_in[0];
    const float* edge_attr = (const float*)d_in[1];
    const int*   ei        = (const int*)d_in[2];
    const float* WA        = (const float*)d_in[3];
    const float* WB        = (const float*)d_in[4];
    const float* gcn_bias  = (const float*)d_in[5];
    const float* w_ih[3] = {(const float*)d_in[6],  (const float*)d_in[10], (const float*)d_in[14]};
    const float* w_hh[3] = {(const float*)d_in[7],  (const float*)d_in[11], (const float*)d_in[15]};
    const float* b_ih[3] = {(const float*)d_in[8],  (const float*)d_in[12], (const float*)d_in[16]};
    const float* b_hh[3] = {(const float*)d_in[9],  (const float*)d_in[13], (const float*)d_in[17]};
    const float* lin_W = (const float*)d_in[18];
    const float* lin_b = (const float*)d_in[19];
    float* out = (float*)d_out;

    char* p = (char*)d_ws;
    auto alloc = [&](size_t bytes) {
        char* r = p;
        p += (bytes + 255) & ~(size_t)255;
        return r;
    };
    int*   deg    = (int*)alloc((size_t)NN * 4);   // ┐ contiguous: one memset
    int*   offs   = (int*)alloc((size_t)NN * 4);   // │
    int*   cursor = (int*)alloc((size_t)NN * 4);   // ┘
    float* dinv   = (float*)alloc((size_t)NN * 4);
    int*   eidx   = (int*)alloc((size_t)NE * 4);
    float* Bself  = (float*)alloc(256 * 4);
    float* hT     = (float*)alloc(2 * NB * 256 * 4);
    float* bias768 = (float*)alloc(3 * G3 * 4);
    float* Ax     = (float*)alloc((size_t)NN * DOUT * 4);
    _Float16* xp16 = (_Float16*)alloc((size_t)NN * G3 * 2);

    _Float16* node16 = (_Float16*)alloc((size_t)NN * DOUT * 2);
    _Float16* yA16   = (_Float16*)alloc((size_t)NN * DOUT * 2);
    _Float16* x16    = (_Float16*)alloc((size_t)NN * DOUT * 2);
    _Float16* yB16   = x16;  // alias: x16 dead after Ax GEMM, yB16 live later
    _Float16* WA16   = (_Float16*)alloc((size_t)256 * 256 * 2);
    _Float16* wih16[3];
    for (int l = 0; l < 3; ++l) wih16[l] = (_Float16*)alloc((size_t)G3 * 256 * 2);
    _Float16* ea16 = (_Float16*)alloc((size_t)NE * DEP * 2);
    _Float16* WB16 = (_Float16*)alloc((size_t)256 * DEP * 2);
    _Float16* Be16 = (_Float16*)alloc((size_t)NE * DOUT * 2);

    // --- CSR build + weight conversions + bias fold ---
    hipMemsetAsync(deg, 0, (size_t)3 * NN * 4, stream);    // deg+offs+cursor
    k_count<<<NE / 256, 256, 0, stream>>>(ei, deg);
    k_scan_offs<<<1, 1024, 0, stream>>>(deg, offs, dinv);
    k_fill<<<NE / 256, 256, 0, stream>>>(ei, offs, cursor, eidx);
    k_bself<<<1, 256, 0, stream>>>(WB, Bself);
    k_bias_fold<<<9, 256, 0, stream>>>(b_ih[0], b_hh[0], b_ih[1], b_hh[1],
                                       b_ih[2], b_hh[2], bias768);
    // total f32->f16 elements: 4194304+65536+3*196608+16777216+16384 = 21643264
    k_cvt_all<<<21136, 256, 0, stream>>>(x, WA, w_ih[0], w_ih[1], w_ih[2],
                                         edge_attr, WB,
                                         x16, WA16, wih16[0], wih16[1], wih16[2],
                                         ea16, WB16);

    // --- GCN ---
    {
        dim3 g(NN / 128, 256 / 128);
        k_gemm16<256, false><<<g, 256, 0, stream>>>(x16, WA16, nullptr, Ax, NN, 256);
    }
    {   // Be[E,256] = ea[E,64] @ WB[256,64]^T  (MFMA, was scalar VALU in k_gcn)
        dim3 g(NE / 128, 256 / 128);
        k_gemm16<64, true><<<g, 256, 0, stream>>>(ea16, WB16, nullptr, Be16, NE, 256);
    }
    k_gcn<<<NN, 256, 0, stream>>>(Ax, Be16, ei, eidx, offs, deg, dinv,
                                  Bself, gcn_bias, node16);

    // --- GRU x3 (layer 2 fuses pooling+linear+softmax) ---
    const _Float16* in16 = node16;
    _Float16* y16_outs[3] = {yA16, yB16, yA16};
    for (int l = 0; l < 3; ++l) {
        dim3 g(NN / 128, G3 / 128);
        k_gemm16<256, true><<<g, 256, 0, stream>>>(in16, wih16[l], bias768 + l * G3,
                                                   xp16, NN, G3);
        k_gru_scan<<<NB, 512, 0, stream>>>(xp16, w_hh[l], b_hh[l], y16_outs[l],
                                           hT, l, lin_W, lin_b, out);
        in16 = y16_outs[l];
    }
}